// Round 2
// baseline (1150.012 us; speedup 1.0000x reference)
//
#include <hip/hip_runtime.h>
#include <hip/hip_bf16.h>

#define NN 40000
#define NE 640000
#define NG 256

typedef __attribute__((ext_vector_type(8))) short bf16x8;
typedef __attribute__((ext_vector_type(4))) float f32x4;

__device__ __forceinline__ unsigned f2b_u(float f){
  unsigned u = __builtin_bit_cast(unsigned, f);
  u += 0x7fffu + ((u >> 16) & 1u);
  return u >> 16;
}
__device__ __forceinline__ float b2f(unsigned short h){
  unsigned u = ((unsigned)h) << 16;
  return __builtin_bit_cast(float, u);
}

// ---------------------------------------------------------------- weight pack
// All matrices stored as Bt[n_out][K] bf16.
// wt layout (shorts):
//   +0 : wEmb [128][128]   (W_embed)
//   per layer l at 16384 + l*180224:
//     +0      U  [128][256]  k<128: Wm rows 128.. (h_rec part), k>=128: Wm rows 256.. (e part)
//     +32768  Qn [128][256]  We rows 128.. / 256..
//     +65536  Pn [128][256]  We rows 0..   / 256..
//     +98304  Ag [128][256]  Wm rows 0..   / 256..
//     +131072 Hn [128][256]  Wh rows 0..   / 128..
//     +163840 Sn [128][128]  We rows 256..
__global__ void pack_k(const float* __restrict__ Wembed, const float* __restrict__ Wm,
                       const float* __restrict__ Wh, const float* __restrict__ We,
                       unsigned short* __restrict__ wt)
{
  const int pid = blockIdx.y;
  const int idx = blockIdx.x * 256 + threadIdx.x;
  const float* src; int rA = 0, rB = 0, K = 256; unsigned short* dst;
  if (pid == 0){ src = Wembed; dst = wt; K = 128; }
  else {
    const int l = (pid - 1) / 6, t = (pid - 1) % 6;
    unsigned short* base = wt + 16384 + l * 180224;
    const float* wm = Wm + (size_t)l * 384 * 128;
    const float* wh = Wh + (size_t)l * 256 * 128;
    const float* we = We + (size_t)l * 384 * 128;
    switch (t){
      case 0:  dst = base;          src = wm; rA = 128; rB = 256; break;
      case 1:  dst = base + 32768;  src = we; rA = 128; rB = 256; break;
      case 2:  dst = base + 65536;  src = we; rA = 0;   rB = 256; break;
      case 3:  dst = base + 98304;  src = wm; rA = 0;   rB = 256; break;
      case 4:  dst = base + 131072; src = wh; rA = 0;   rB = 128; break;
      default: dst = base + 163840; src = we; rA = 256; K = 128;  break;
    }
  }
  if (idx >= 128 * K) return;
  int j, k;
  if (K == 256){ j = idx >> 8; k = idx & 255; } else { j = idx >> 7; k = idx & 127; }
  const int row = (k < 128) ? (rA + k) : (rB + k - 128);
  dst[j * K + k] = (unsigned short)f2b_u(src[(size_t)row * 128 + j]);
}

// --------------------------------------------- layer vectors r_l, c_l (exact f32)
// c_0 = 0; r_l = bm_l + c_l@Wm3_l ; c_{l+1} = c_l@We3_l + be_l
__global__ void vec_k(const float* __restrict__ Wm, const float* __restrict__ bm,
                      const float* __restrict__ We, const float* __restrict__ be,
                      float* __restrict__ rvec)
{
  __shared__ float c[128];
  const int j = threadIdx.x;
  c[j] = 0.f;
  __syncthreads();
  for (int l = 0; l < 4; ++l){
    const float* wm3 = Wm + (size_t)l * 384 * 128 + 256 * 128;
    const float* we3 = We + (size_t)l * 384 * 128 + 256 * 128;
    float r = bm[l * 128 + j];
    float cn = be[l * 128 + j];
    for (int k = 0; k < 128; ++k){
      const float ck = c[k];
      r  += ck * wm3[k * 128 + j];
      cn += ck * we3[k * 128 + j];
    }
    rvec[l * 128 + j] = r;
    __syncthreads();
    c[j] = cn;
    __syncthreads();
  }
}

// ------------------------------------------------------------------ GEMM
template<int AT>
__device__ __forceinline__ void stage_A(const void* __restrict__ Ain, int m0, int r0,
                                        int chunk, int M, unsigned short* As)
{
  #pragma unroll
  for (int rr = 0; rr < 8; ++rr){
    const int r = r0 + rr * 16;
    const int gr = m0 + r;
    uint4 va = make_uint4(0u, 0u, 0u, 0u);
    if (gr < M){
      if (AT == 0){
        va = *(const uint4*)((const unsigned short*)Ain + ((size_t)gr << 7) + chunk * 8);
      } else {
        const float* Af = (const float*)Ain + ((size_t)gr << 7) + chunk * 8;
        const float4 f0 = *(const float4*)Af;
        const float4 f1 = *(const float4*)(Af + 4);
        va.x = f2b_u(f0.x) | (f2b_u(f0.y) << 16);
        va.y = f2b_u(f0.z) | (f2b_u(f0.w) << 16);
        va.z = f2b_u(f1.x) | (f2b_u(f1.y) << 16);
        va.w = f2b_u(f1.z) | (f2b_u(f1.w) << 16);
      }
    }
    *(uint4*)&As[r * 128 + ((chunk ^ (r & 7)) << 3)] = va;
  }
}

// C[M x 128] = [A0 | A1] @ Bt^T, A panels each M x 128 (separate buffers).
// AT*: 0 = bf16, 1 = f32.  NK: 1 or 2 panels.
// EPI 0: f32 out = acc + bias;  EPI 1: bf16 out = acc;
// EPI 2: bf16 out = acc + deg(row)*(b2f(Ub[row,col]) + rvec[col])   (deg from rp)
template<int AT0, int AT1, int NK, int EPI>
__global__ __launch_bounds__(256, 2) void gemm_k(
    const void* __restrict__ A0, const void* __restrict__ A1,
    const unsigned short* __restrict__ Bt, int M, void* __restrict__ outp,
    const float* __restrict__ bias, const unsigned short* __restrict__ Ub,
    const float* __restrict__ rvec, const int* __restrict__ rp)
{
  __shared__ unsigned short As[128 * 128];
  __shared__ unsigned short Bs[128 * 128];
  const int tid = threadIdx.x;
  const int m0 = blockIdx.x * 128;
  const int lane = tid & 63, wave = tid >> 6;
  const int qm = (wave & 1) << 6, qn = (wave >> 1) << 6;
  const int lr = lane & 15, lkc = lane >> 4;
  const int chunk = tid & 15, r0 = tid >> 4;
  f32x4 acc[4][4] = {};

  auto stage_B = [&](int k0){
    #pragma unroll
    for (int rr = 0; rr < 8; ++rr){
      const int r = r0 + rr * 16;
      *(uint4*)&Bs[r * 128 + ((chunk ^ (r & 7)) << 3)] =
          *(const uint4*)(Bt + (size_t)r * (NK * 128) + k0 + chunk * 8);
    }
  };
  auto do_mfma = [&](){
    #pragma unroll
    for (int kk = 0; kk < 4; ++kk){
      const int kc = kk * 4 + lkc;
      bf16x8 af[4], bfr[4];
      #pragma unroll
      for (int mi = 0; mi < 4; ++mi){
        const int r = qm + mi * 16 + lr;
        af[mi] = *(const bf16x8*)&As[r * 128 + ((kc ^ (r & 7)) << 3)];
      }
      #pragma unroll
      for (int ni = 0; ni < 4; ++ni){
        const int r = qn + ni * 16 + lr;
        bfr[ni] = *(const bf16x8*)&Bs[r * 128 + ((kc ^ (r & 7)) << 3)];
      }
      #pragma unroll
      for (int mi = 0; mi < 4; ++mi)
        #pragma unroll
        for (int ni = 0; ni < 4; ++ni)
          acc[mi][ni] = __builtin_amdgcn_mfma_f32_16x16x32_bf16(af[mi], bfr[ni], acc[mi][ni], 0, 0, 0);
    }
  };

  stage_A<AT0>(A0, m0, r0, chunk, M, As);
  stage_B(0);
  __syncthreads();
  do_mfma();
  if (NK == 2){
    __syncthreads();
    stage_A<AT1>(A1, m0, r0, chunk, M, As);
    stage_B(128);
    __syncthreads();
    do_mfma();
  }

  const int rbase = (lane >> 4) << 2;
  #pragma unroll
  for (int mi = 0; mi < 4; ++mi){
    #pragma unroll
    for (int r = 0; r < 4; ++r){
      const int gr = m0 + qm + mi * 16 + rbase + r;
      if (gr >= M) continue;
      const size_t ro = (size_t)gr << 7;
      float degf = 0.f;
      if (EPI == 2) degf = (float)(rp[gr + 1] - rp[gr]);
      #pragma unroll
      for (int ni = 0; ni < 4; ++ni){
        const int col = qn + ni * 16 + lr;
        float v = acc[mi][ni][r];
        if (EPI == 0){
          ((float*)outp)[ro + col] = v + bias[col];
        } else if (EPI == 1){
          ((unsigned short*)outp)[ro + col] = (unsigned short)f2b_u(v);
        } else {
          v += degf * (b2f(Ub[ro + col]) + rvec[col]);
          ((unsigned short*)outp)[ro + col] = (unsigned short)f2b_u(v);
        }
      }
    }
  }
}

// ------------------------------------------------------------ CSR build utils
__global__ void hist_k(const int* __restrict__ idx, int* __restrict__ cnt, int n){
  const int i = blockIdx.x * 256 + threadIdx.x;
  if (i < n) atomicAdd(&cnt[idx[i]], 1);
}
__global__ void copy_k(const int* __restrict__ src, int* __restrict__ dst, int n){
  const int i = blockIdx.x * 256 + threadIdx.x;
  if (i < n) dst[i] = src[i];
}
__global__ void fill_k(const int* __restrict__ rec, int* __restrict__ cursor,
                       int* __restrict__ perm){
  const int i = blockIdx.x * 256 + threadIdx.x;
  if (i < NE){
    const int p = atomicAdd(&cursor[rec[i]], 1);
    perm[p] = i;
  }
}
// single-block exclusive scan: out[0]=0, out[i+1]=sum(in[0..i])
__global__ void scan_k(const int* __restrict__ in, int* __restrict__ out, int n){
  __shared__ int tmp[1024];
  __shared__ int carry_s;
  const int t = threadIdx.x;
  if (t == 0) carry_s = 0;
  __syncthreads();
  for (int base = 0; base < n; base += 1024){
    const int i = base + t;
    int v = (i < n) ? in[i] : 0;
    tmp[t] = v; __syncthreads();
    for (int off = 1; off < 1024; off <<= 1){
      const int u = (t >= off) ? tmp[t - off] : 0;
      __syncthreads();
      tmp[t] += u;
      __syncthreads();
    }
    const int c = carry_s;
    if (i < n) out[i + 1] = c + tmp[t];
    __syncthreads();
    if (t == 1023) carry_s = c + tmp[1023];
    __syncthreads();
  }
  if (t == 0) out[0] = 0;
}

// ---------------------------------------------- raw-e segment sum (N x 16)
__global__ void sraw_k(const int* __restrict__ rp, const int* __restrict__ perm,
                       const float* __restrict__ eraw, float* __restrict__ sraw)
{
  const int n = blockIdx.x * 16 + (threadIdx.x >> 4);
  const int l16 = threadIdx.x & 15;
  float acc = 0.f;
  const int beg = rp[n], end = rp[n + 1];
  for (int j = beg; j < end; ++j)
    acc += eraw[(size_t)perm[j] * 16 + l16];
  sraw[(size_t)n * 16 + l16] = acc;
}

// S0M_0[n] = sraw[n]@W_eembed + deg[n]*b_eembed   (bf16 out)
__global__ void s0_k(const float* __restrict__ sraw, const float* __restrict__ W,
                     const float* __restrict__ b, const int* __restrict__ rp,
                     unsigned short* __restrict__ S0M)
{
  __shared__ float Ws[2048];
  __shared__ float bs[128];
  const int t = threadIdx.x;
  for (int i = t; i < 2048; i += 256) Ws[i] = W[i];
  if (t < 128) bs[t] = b[t];
  __syncthreads();
  const int half = t >> 7, j = t & 127;
  const int n = blockIdx.x * 2 + half;
  const float* sr = sraw + (size_t)n * 16;
  const float deg = (float)(rp[n + 1] - rp[n]);
  float acc = deg * bs[j];
  #pragma unroll
  for (int k = 0; k < 16; ++k) acc += sr[k] * Ws[k * 128 + j];
  S0M[((size_t)n << 7) + j] = (unsigned short)f2b_u(acc);
}

// -------------------------------- per-node gather: t = sum h[send], tPV = sum P[send] + S0M
__global__ void gather_k(const int* __restrict__ rp, const int* __restrict__ perm,
                         const int* __restrict__ send,
                         const float* __restrict__ h, const unsigned short* __restrict__ P,
                         const unsigned short* __restrict__ S0M,
                         unsigned short* __restrict__ tb, unsigned short* __restrict__ tPV)
{
  const int n = blockIdx.x * 4 + (threadIdx.x >> 6);
  const int lane = threadIdx.x & 63;
  const int beg = rp[n], end = rp[n + 1];
  const size_t co = ((size_t)n << 7) + 2 * lane;
  float t0 = 0.f, t1 = 0.f;
  const unsigned sv = *(const unsigned*)(S0M + co);
  float p0 = b2f((unsigned short)(sv & 0xffffu));
  float p1 = b2f((unsigned short)(sv >> 16));
  for (int j = beg; j < end; ++j){
    const int sd = send[perm[j]];
    const float2 hv = *(const float2*)(h + ((size_t)sd << 7) + 2 * lane);
    t0 += hv.x; t1 += hv.y;
    const unsigned pv = *(const unsigned*)(P + ((size_t)sd << 7) + 2 * lane);
    p0 += b2f((unsigned short)(pv & 0xffffu));
    p1 += b2f((unsigned short)(pv >> 16));
  }
  *(unsigned*)(tb + co)  = f2b_u(t0) | (f2b_u(t1) << 16);
  *(unsigned*)(tPV + co) = f2b_u(p0) | (f2b_u(p1) << 16);
}

// ------------------------------------------------------------------ pooling
__global__ void pool_k(const int* __restrict__ gptr, const float* __restrict__ h,
                       float* __restrict__ out)
{
  const int g = blockIdx.x * 4 + (threadIdx.x >> 6);
  const int lane = threadIdx.x & 63;
  float a0 = 0.f, a1 = 0.f;
  for (int n = gptr[g]; n < gptr[g + 1]; ++n){
    const float2 hv = *(const float2*)(h + ((size_t)n << 7) + 2 * lane);
    a0 += hv.x; a1 += hv.y;
  }
  float2 r; r.x = a0; r.y = a1;
  *(float2*)(out + (size_t)g * 128 + 2 * lane) = r;
}

// =====================================================================
extern "C" void kernel_launch(void* const* d_in, const int* in_sizes, int n_in,
                              void* d_out, int out_size, void* d_ws, size_t ws_size,
                              hipStream_t stream)
{
  const float* h_in     = (const float*)d_in[0];
  const float* e_in     = (const float*)d_in[1];
  const int*   eidx     = (const int*)d_in[2];
  const int*   batch    = (const int*)d_in[3];
  const float* W_embed  = (const float*)d_in[4];
  const float* b_embed  = (const float*)d_in[5];
  const float* W_eembed = (const float*)d_in[6];
  const float* b_eembed = (const float*)d_in[7];
  const float* Wm       = (const float*)d_in[8];
  const float* bm       = (const float*)d_in[9];
  const float* Wh       = (const float*)d_in[10];
  const float* bh       = (const float*)d_in[11];
  const float* We       = (const float*)d_in[12];
  const float* be       = (const float*)d_in[13];
  const int* send = eidx;
  const int* rec  = eidx + NE;

  char* ws = (char*)d_ws;
  size_t off = 0;
  auto alloc = [&](size_t bytes) -> char* {
    char* p = ws + off;
    off = (off + bytes + 255) & ~(size_t)255;
    return p;
  };
  unsigned short* wt   = (unsigned short*)alloc((size_t)737280 * 2);     // 1.47 MB
  float*          hbuf = (float*)alloc((size_t)NN * 128 * 4);            // 20.5 MB
  unsigned short* P    = (unsigned short*)alloc((size_t)NN * 128 * 2);   // 10.2 MB
  unsigned short* Q    = (unsigned short*)alloc((size_t)NN * 128 * 2);
  unsigned short* S0M  = (unsigned short*)alloc((size_t)NN * 128 * 2);
  unsigned short* tb   = (unsigned short*)alloc((size_t)NN * 128 * 2);
  unsigned short* tPV  = (unsigned short*)alloc((size_t)NN * 128 * 2);
  unsigned short* Uagg = (unsigned short*)alloc((size_t)NN * 128 * 2);
  float*          sraw = (float*)alloc((size_t)NN * 16 * 4);             // 2.56 MB
  float*          rvec = (float*)alloc((size_t)512 * 4);
  int* deg     = (int*)alloc((size_t)(NN + NG) * 4);
  int* gcnt    = deg + NN;
  int* row_ptr = (int*)alloc((size_t)(NN + 1) * 4);
  int* cursor  = (int*)alloc((size_t)NN * 4);
  int* perm    = (int*)alloc((size_t)NE * 4);
  int* gptr    = (int*)alloc((size_t)(NG + 1) * 4);

  if (off > ws_size) return;  // diagnostic guard: fail numerically, not with a fault

  const dim3 B256(256);

  pack_k<<<dim3(128, 25), B256, 0, stream>>>(W_embed, Wm, Wh, We, wt);
  vec_k<<<dim3(1), dim3(128), 0, stream>>>(Wm, bm, We, be, rvec);

  hipMemsetAsync(P, 0, (size_t)NN * 128 * 2, stream);
  hipMemsetAsync(Q, 0, (size_t)NN * 128 * 2, stream);
  hipMemsetAsync(deg, 0, (size_t)(NN + NG) * 4, stream);

  // h_0 = h_in @ W_embed + b_embed  (f32 out)
  gemm_k<1, 0, 1, 0><<<dim3(313), B256, 0, stream>>>(h_in, nullptr, wt, NN, hbuf,
      b_embed, nullptr, nullptr, nullptr);

  // CSR over rec + graph boundaries
  hist_k<<<dim3((NE + 255) / 256), B256, 0, stream>>>(rec, deg, NE);
  hist_k<<<dim3((NN + 255) / 256), B256, 0, stream>>>(batch, gcnt, NN);
  scan_k<<<dim3(1), dim3(1024), 0, stream>>>(deg, row_ptr, NN);
  scan_k<<<dim3(1), dim3(1024), 0, stream>>>(gcnt, gptr, NG);
  copy_k<<<dim3((NN + 255) / 256), B256, 0, stream>>>(row_ptr, cursor, NN);
  fill_k<<<dim3((NE + 255) / 256), B256, 0, stream>>>(rec, cursor, perm);

  // S0M_0 = segsum(e_raw)@W_eembed + deg*b_eembed
  sraw_k<<<dim3(NN / 16), B256, 0, stream>>>(row_ptr, perm, e_in, sraw);
  s0_k<<<dim3(NN / 2), B256, 0, stream>>>(sraw, W_eembed, b_eembed, row_ptr, S0M);

  for (int l = 0; l < 4; ++l){
    unsigned short* base = wt + 16384 + l * 180224;
    const unsigned short* wtU = base;
    const unsigned short* wtQ = base + 32768;
    const unsigned short* wtP = base + 65536;
    const unsigned short* wtA = base + 98304;
    const unsigned short* wtH = base + 131072;
    const unsigned short* wtS = base + 163840;

    // t_l, tPV_l = sum h[send], sum P[send] + S0M
    gather_k<<<dim3(NN / 4), B256, 0, stream>>>(row_ptr, perm, send, hbuf, P, S0M, tb, tPV);
    // U_l = h@Wm2 + Q@Wm3
    gemm_k<1, 0, 2, 1><<<dim3(313), B256, 0, stream>>>(hbuf, Q, wtU, NN, Uagg,
        nullptr, nullptr, nullptr, nullptr);
    // agg = t@Wm1 + tPV@Wm3 + deg*(U + r_l)   (writes over U buffer — element-wise safe)
    gemm_k<0, 0, 2, 2><<<dim3(313), B256, 0, stream>>>(tb, tPV, wtA, NN, Uagg,
        nullptr, Uagg, rvec + l * 128, row_ptr);
    if (l < 3){
      // Q_{l+1} = h@We2 + Q@We3   (in-place on Q)
      gemm_k<1, 0, 2, 1><<<dim3(313), B256, 0, stream>>>(hbuf, Q, wtQ, NN, Q,
          nullptr, nullptr, nullptr, nullptr);
      // P_{l+1} = h@We1 + P@We3   (in-place on P)
      gemm_k<1, 0, 2, 1><<<dim3(313), B256, 0, stream>>>(hbuf, P, wtP, NN, P,
          nullptr, nullptr, nullptr, nullptr);
      // S0M_{l+1} = S0M@We3       (in-place)
      gemm_k<0, 0, 1, 1><<<dim3(313), B256, 0, stream>>>(S0M, nullptr, wtS, NN, S0M,
          nullptr, nullptr, nullptr, nullptr);
    }
    // h_{l+1} = h@Wh1 + agg@Wh2 + bh   (in-place on h, launched last)
    gemm_k<1, 0, 2, 0><<<dim3(313), B256, 0, stream>>>(hbuf, Uagg, wtH, NN, hbuf,
        bh + l * 128, nullptr, nullptr, nullptr);
  }

  pool_k<<<dim3(NG / 4), B256, 0, stream>>>(gptr, hbuf, (float*)d_out);
}

// Round 3
// 797.508 us; speedup vs baseline: 1.4420x; 1.4420x over previous
//
#include <hip/hip_runtime.h>
#include <hip/hip_bf16.h>

#define NN 40000
#define NE 640000
#define NG 256

typedef __attribute__((ext_vector_type(8))) short bf16x8;
typedef __attribute__((ext_vector_type(4))) float f32x4;

__device__ __forceinline__ unsigned f2b_u(float f){
  unsigned u = __builtin_bit_cast(unsigned, f);
  u += 0x7fffu + ((u >> 16) & 1u);
  return u >> 16;
}
__device__ __forceinline__ float b2f(unsigned short h){
  unsigned u = ((unsigned)h) << 16;
  return __builtin_bit_cast(float, u);
}

// ---------------------------------------------------------------- weight pack
// All as Bt[n_out=128][K] bf16.
// wt layout (shorts):
//   +0 : wEmb [128][128]  (W_embed)
//   per layer l at 16384 + l*163840, five [128][256] mats (t = 0..4):
//     t0 G1.y0  U    : [Wm2 ; Wm3]
//     t1 G1.y1  Qnew : [We2 ; We3]
//     t2 G2.y0  agg  : [Wm1 ; Wm3]
//     t3 G2.y1  TPS  : [We1 ; We3]
//     t4 G4     hnew : [Wh1 ; Wh2]
__global__ void pack_k(const float* __restrict__ Wembed, const float* __restrict__ Wm,
                       const float* __restrict__ Wh, const float* __restrict__ We,
                       unsigned short* __restrict__ wt)
{
  const int pid = blockIdx.y;
  const int idx = blockIdx.x * 256 + threadIdx.x;
  const float* src; int rA = 0, rB = 0, K = 256; unsigned short* dst;
  if (pid == 0){ src = Wembed; dst = wt; K = 128; }
  else {
    const int l = (pid - 1) / 5, t = (pid - 1) % 5;
    dst = wt + 16384 + l * 163840 + t * 32768;
    const float* wm = Wm + (size_t)l * 384 * 128;
    const float* wh = Wh + (size_t)l * 256 * 128;
    const float* we = We + (size_t)l * 384 * 128;
    switch (t){
      case 0:  src = wm; rA = 128; rB = 256; break;
      case 1:  src = we; rA = 128; rB = 256; break;
      case 2:  src = wm; rA = 0;   rB = 256; break;
      case 3:  src = we; rA = 0;   rB = 256; break;
      default: src = wh; rA = 0;   rB = 128; break;
    }
  }
  if (idx >= 128 * K) return;
  int j, k;
  if (K == 256){ j = idx >> 8; k = idx & 255; } else { j = idx >> 7; k = idx & 127; }
  const int row = (k < 128) ? (rA + k) : (rB + k - 128);
  dst[j * K + k] = (unsigned short)f2b_u(src[(size_t)row * 128 + j]);
}

// --------------------------------------------- layer vectors r_l (exact f32)
// c_0 = 0; r_l = bm_l + c_l@Wm3_l ; c_{l+1} = c_l@We3_l + be_l
__global__ void vec_k(const float* __restrict__ Wm, const float* __restrict__ bm,
                      const float* __restrict__ We, const float* __restrict__ be,
                      float* __restrict__ rvec)
{
  __shared__ float c[128];
  const int j = threadIdx.x;
  c[j] = 0.f;
  __syncthreads();
  for (int l = 0; l < 4; ++l){
    const float* wm3 = Wm + (size_t)l * 384 * 128 + 256 * 128;
    const float* we3 = We + (size_t)l * 384 * 128 + 256 * 128;
    float r = bm[l * 128 + j];
    float cn = be[l * 128 + j];
    for (int k = 0; k < 128; ++k){
      const float ck = c[k];
      r  += ck * wm3[k * 128 + j];
      cn += ck * we3[k * 128 + j];
    }
    rvec[l * 128 + j] = r;
    __syncthreads();
    c[j] = cn;
    __syncthreads();
  }
}

// ------------------------------------------------------------------ GEMM
// C[M x 128] = [A0 | A1] @ Bt^T. blockIdx.y selects B-matrix (BtBase + y*NK*16384),
// output (out0/out1) and epilogue (E0/E1).
// AT0: 0 = A0 bf16, 1 = A0 f32. A1 always bf16.
// EPI 0: bf16 = acc
// EPI 1: bf16 = acc + deg(row)*(b2f(Ub[row,col]) + rvec[col])   (deg from rp)
// EPI 2: bf16 = acc + bias[col]
template<int AT0, int NK, int E0, int E1>
__global__ __launch_bounds__(256, 2) void gemm2_k(
    const void* __restrict__ A0, const void* __restrict__ A1,
    const unsigned short* __restrict__ BtBase, int M,
    void* __restrict__ out0, void* __restrict__ out1,
    const float* __restrict__ bias,
    const unsigned short* __restrict__ Ub,
    const float* __restrict__ rvec, const int* __restrict__ rp)
{
  __shared__ unsigned short As[128 * 128];
  __shared__ unsigned short Bs[128 * 128];
  const int y = blockIdx.y;
  const unsigned short* Bt = BtBase + (size_t)y * (NK * 128 * 128);
  const int tid = threadIdx.x;
  const int m0 = blockIdx.x * 128;
  const int lane = tid & 63, wave = tid >> 6;
  const int qm = (wave & 1) << 6, qn = (wave >> 1) << 6;
  const int lr = lane & 15, lkc = lane >> 4;
  const int chunk = tid & 15, r0 = tid >> 4;
  f32x4 acc[4][4] = {};

  for (int p = 0; p < NK; ++p){
    if (p) __syncthreads();
    const void* Ain = p ? A1 : A0;
    const int at = p ? 0 : AT0;
    #pragma unroll
    for (int rr = 0; rr < 8; ++rr){
      const int r = r0 + rr * 16;
      const int gr = m0 + r;
      uint4 va = make_uint4(0u, 0u, 0u, 0u);
      if (gr < M){
        if (at == 0){
          va = *(const uint4*)((const unsigned short*)Ain + ((size_t)gr << 7) + chunk * 8);
        } else {
          const float* Af = (const float*)Ain + ((size_t)gr << 7) + chunk * 8;
          const float4 f0 = *(const float4*)Af;
          const float4 f1 = *(const float4*)(Af + 4);
          va.x = f2b_u(f0.x) | (f2b_u(f0.y) << 16);
          va.y = f2b_u(f0.z) | (f2b_u(f0.w) << 16);
          va.z = f2b_u(f1.x) | (f2b_u(f1.y) << 16);
          va.w = f2b_u(f1.z) | (f2b_u(f1.w) << 16);
        }
      }
      *(uint4*)&As[r * 128 + ((chunk ^ (r & 7)) << 3)] = va;
      *(uint4*)&Bs[r * 128 + ((chunk ^ (r & 7)) << 3)] =
          *(const uint4*)(Bt + (size_t)r * (NK * 128) + p * 128 + chunk * 8);
    }
    __syncthreads();
    #pragma unroll
    for (int kk = 0; kk < 4; ++kk){
      const int kc = kk * 4 + lkc;
      bf16x8 af[4], bfr[4];
      #pragma unroll
      for (int mi = 0; mi < 4; ++mi){
        const int r = qm + mi * 16 + lr;
        af[mi] = *(const bf16x8*)&As[r * 128 + ((kc ^ (r & 7)) << 3)];
      }
      #pragma unroll
      for (int ni = 0; ni < 4; ++ni){
        const int r = qn + ni * 16 + lr;
        bfr[ni] = *(const bf16x8*)&Bs[r * 128 + ((kc ^ (r & 7)) << 3)];
      }
      #pragma unroll
      for (int mi = 0; mi < 4; ++mi)
        #pragma unroll
        for (int ni = 0; ni < 4; ++ni)
          acc[mi][ni] = __builtin_amdgcn_mfma_f32_16x16x32_bf16(af[mi], bfr[ni], acc[mi][ni], 0, 0, 0);
    }
  }

  const int epi = (y == 0) ? E0 : E1;
  unsigned short* outp = (unsigned short*)(y ? out1 : out0);
  const int rbase = (lane >> 4) << 2;
  #pragma unroll
  for (int mi = 0; mi < 4; ++mi){
    #pragma unroll
    for (int r = 0; r < 4; ++r){
      const int gr = m0 + qm + mi * 16 + rbase + r;
      if (gr >= M) continue;
      const size_t ro = (size_t)gr << 7;
      float degf = 0.f;
      if (epi == 1) degf = (float)(rp[gr + 1] - rp[gr]);
      #pragma unroll
      for (int ni = 0; ni < 4; ++ni){
        const int col = qn + ni * 16 + lr;
        float v = acc[mi][ni][r];
        if (epi == 1) v += degf * (b2f(Ub[ro + col]) + rvec[col]);
        if (epi == 2) v += bias[col];
        outp[ro + col] = (unsigned short)f2b_u(v);
      }
    }
  }
}

// ------------------------------------------------------------ CSR build utils
__global__ void hist_k(const int* __restrict__ idx, int* __restrict__ cnt, int n){
  const int i = blockIdx.x * 256 + threadIdx.x;
  if (i < n) atomicAdd(&cnt[idx[i]], 1);
}
__global__ void copy_k(const int* __restrict__ src, int* __restrict__ dst, int n){
  const int i = blockIdx.x * 256 + threadIdx.x;
  if (i < n) dst[i] = src[i];
}
__global__ void fill_k(const int* __restrict__ rec, const int* __restrict__ send,
                       int* __restrict__ cursor, int* __restrict__ perm,
                       int* __restrict__ sperm){
  const int i = blockIdx.x * 256 + threadIdx.x;
  if (i < NE){
    const int p = atomicAdd(&cursor[rec[i]], 1);
    perm[p] = i;
    sperm[p] = send[i];
  }
}
// one-block exclusive scan: out[0]=0, out[i+1]=inclusive prefix. Chunk-per-thread.
__global__ void scan_k(const int* __restrict__ in, int* __restrict__ out, int n){
  __shared__ int tmp[1024];
  const int t = threadIdx.x;
  const int CH = (n + 1023) >> 10;
  const int base = t * CH;
  const int lim = (base + CH < n) ? base + CH : n;
  int s = 0;
  for (int i = base; i < lim; ++i) s += in[i];
  tmp[t] = s; __syncthreads();
  for (int off = 1; off < 1024; off <<= 1){
    const int u = (t >= off) ? tmp[t - off] : 0;
    __syncthreads();
    tmp[t] += u;
    __syncthreads();
  }
  int run = t ? tmp[t - 1] : 0;
  for (int i = base; i < lim; ++i){ run += in[i]; out[i + 1] = run; }
  if (t == 0) out[0] = 0;
}

// ---------------------------------------------- raw-e segment sum (N x 16)
__global__ void sraw_k(const int* __restrict__ rp, const int* __restrict__ perm,
                       const float* __restrict__ eraw, float* __restrict__ sraw)
{
  const int n = blockIdx.x * 16 + (threadIdx.x >> 4);
  const int l16 = threadIdx.x & 15;
  float acc = 0.f;
  const int beg = rp[n], end = rp[n + 1];
  for (int j = beg; j < end; ++j)
    acc += eraw[(size_t)perm[j] * 16 + l16];
  sraw[(size_t)n * 16 + l16] = acc;
}

// TPS_0[n] = sraw[n]@W_eembed + deg[n]*b_eembed   (bf16 out)
__global__ void s0_k(const float* __restrict__ sraw, const float* __restrict__ W,
                     const float* __restrict__ b, const int* __restrict__ rp,
                     unsigned short* __restrict__ TPS)
{
  __shared__ float Ws[2048];
  __shared__ float bs[128];
  const int t = threadIdx.x;
  for (int i = t; i < 2048; i += 256) Ws[i] = W[i];
  if (t < 128) bs[t] = b[t];
  __syncthreads();
  const int half = t >> 7, j = t & 127;
  const int n = blockIdx.x * 2 + half;
  const float* sr = sraw + (size_t)n * 16;
  const float deg = (float)(rp[n + 1] - rp[n]);
  float acc = deg * bs[j];
  #pragma unroll
  for (int k = 0; k < 16; ++k) acc += sr[k] * Ws[k * 128 + j];
  TPS[((size_t)n << 7) + j] = (unsigned short)f2b_u(acc);
}

// -------------------------------- per-node gather: t[n] = sum_{e: rec=n} h[send[e]]
__global__ void gather_k(const int* __restrict__ rp, const int* __restrict__ sperm,
                         const unsigned short* __restrict__ hb,
                         unsigned short* __restrict__ tb)
{
  const int n = blockIdx.x * 4 + (threadIdx.x >> 6);
  const int lane = threadIdx.x & 63;
  const int beg = rp[n], end = rp[n + 1];
  float t0 = 0.f, t1 = 0.f;
  for (int j0 = beg; j0 < end; j0 += 64){
    const int m = (end - j0 < 64) ? (end - j0) : 64;
    const int myidx = (j0 + lane < end) ? sperm[j0 + lane] : 0;
    int k = 0;
    for (; k + 4 <= m; k += 4){
      const int s0 = __shfl(myidx, k);
      const int s1 = __shfl(myidx, k + 1);
      const int s2 = __shfl(myidx, k + 2);
      const int s3 = __shfl(myidx, k + 3);
      const unsigned v0 = *(const unsigned*)(hb + ((size_t)s0 << 7) + 2 * lane);
      const unsigned v1 = *(const unsigned*)(hb + ((size_t)s1 << 7) + 2 * lane);
      const unsigned v2 = *(const unsigned*)(hb + ((size_t)s2 << 7) + 2 * lane);
      const unsigned v3 = *(const unsigned*)(hb + ((size_t)s3 << 7) + 2 * lane);
      t0 += b2f((unsigned short)(v0 & 0xffffu)) + b2f((unsigned short)(v1 & 0xffffu))
          + b2f((unsigned short)(v2 & 0xffffu)) + b2f((unsigned short)(v3 & 0xffffu));
      t1 += b2f((unsigned short)(v0 >> 16)) + b2f((unsigned short)(v1 >> 16))
          + b2f((unsigned short)(v2 >> 16)) + b2f((unsigned short)(v3 >> 16));
    }
    for (; k < m; ++k){
      const int s = __shfl(myidx, k);
      const unsigned v = *(const unsigned*)(hb + ((size_t)s << 7) + 2 * lane);
      t0 += b2f((unsigned short)(v & 0xffffu));
      t1 += b2f((unsigned short)(v >> 16));
    }
  }
  *(unsigned*)(tb + ((size_t)n << 7) + 2 * lane) = f2b_u(t0) | (f2b_u(t1) << 16);
}

// ------------------------------------------------------------------ pooling
__global__ void pool_k(const int* __restrict__ gptr, const unsigned short* __restrict__ hb,
                       float* __restrict__ out)
{
  const int g = blockIdx.x * 4 + (threadIdx.x >> 6);
  const int lane = threadIdx.x & 63;
  float a0 = 0.f, a1 = 0.f;
  for (int n = gptr[g]; n < gptr[g + 1]; ++n){
    const unsigned v = *(const unsigned*)(hb + ((size_t)n << 7) + 2 * lane);
    a0 += b2f((unsigned short)(v & 0xffffu));
    a1 += b2f((unsigned short)(v >> 16));
  }
  float2 r; r.x = a0; r.y = a1;
  *(float2*)(out + (size_t)g * 128 + 2 * lane) = r;
}

// =====================================================================
extern "C" void kernel_launch(void* const* d_in, const int* in_sizes, int n_in,
                              void* d_out, int out_size, void* d_ws, size_t ws_size,
                              hipStream_t stream)
{
  const float* h_in     = (const float*)d_in[0];
  const float* e_in     = (const float*)d_in[1];
  const int*   eidx     = (const int*)d_in[2];
  const int*   batch    = (const int*)d_in[3];
  const float* W_embed  = (const float*)d_in[4];
  const float* b_embed  = (const float*)d_in[5];
  const float* W_eembed = (const float*)d_in[6];
  const float* b_eembed = (const float*)d_in[7];
  const float* Wm       = (const float*)d_in[8];
  const float* bm       = (const float*)d_in[9];
  const float* Wh       = (const float*)d_in[10];
  const float* bh       = (const float*)d_in[11];
  const float* We       = (const float*)d_in[12];
  const float* be       = (const float*)d_in[13];
  const int* send = eidx;
  const int* rec  = eidx + NE;

  char* ws = (char*)d_ws;
  size_t off = 0;
  auto alloc = [&](size_t bytes) -> char* {
    char* p = ws + off;
    off = (off + bytes + 255) & ~(size_t)255;
    return p;
  };
  unsigned short* wt   = (unsigned short*)alloc((size_t)(16384 + 20 * 32768) * 2);
  unsigned short* hb   = (unsigned short*)alloc((size_t)NN * 128 * 2);
  unsigned short* Q    = (unsigned short*)alloc((size_t)NN * 128 * 2);
  unsigned short* TPS  = (unsigned short*)alloc((size_t)NN * 128 * 2);
  unsigned short* tb   = (unsigned short*)alloc((size_t)NN * 128 * 2);
  unsigned short* U    = (unsigned short*)alloc((size_t)NN * 128 * 2);
  unsigned short* agg  = (unsigned short*)alloc((size_t)NN * 128 * 2);
  float*          sraw = (float*)alloc((size_t)NN * 16 * 4);
  float*          rvec = (float*)alloc((size_t)512 * 4);
  int* deg     = (int*)alloc((size_t)(NN + NG) * 4);
  int* gcnt    = deg + NN;
  int* row_ptr = (int*)alloc((size_t)(NN + 1) * 4);
  int* cursor  = (int*)alloc((size_t)NN * 4);
  int* perm    = (int*)alloc((size_t)NE * 4);
  int* sperm   = (int*)alloc((size_t)NE * 4);
  int* gptr    = (int*)alloc((size_t)(NG + 1) * 4);

  if (off > ws_size) return;  // fail numerically, not with a fault

  const dim3 B256(256);

  pack_k<<<dim3(128, 21), B256, 0, stream>>>(W_embed, Wm, Wh, We, wt);
  vec_k<<<dim3(1), dim3(128), 0, stream>>>(Wm, bm, We, be, rvec);

  hipMemsetAsync(Q, 0, (size_t)NN * 128 * 2, stream);
  hipMemsetAsync(deg, 0, (size_t)(NN + NG) * 4, stream);

  // h_0 = h_in @ W_embed + b_embed  (bf16)
  gemm2_k<1, 1, 2, 2><<<dim3(313), B256, 0, stream>>>(h_in, nullptr, wt, NN,
      hb, nullptr, b_embed, nullptr, nullptr, nullptr);

  // CSR over rec + graph boundaries
  hist_k<<<dim3((NE + 255) / 256), B256, 0, stream>>>(rec, deg, NE);
  hist_k<<<dim3((NN + 255) / 256), B256, 0, stream>>>(batch, gcnt, NN);
  scan_k<<<dim3(1), dim3(1024), 0, stream>>>(deg, row_ptr, NN);
  scan_k<<<dim3(1), dim3(1024), 0, stream>>>(gcnt, gptr, NG);
  copy_k<<<dim3((NN + 255) / 256), B256, 0, stream>>>(row_ptr, cursor, NN);
  fill_k<<<dim3((NE + 255) / 256), B256, 0, stream>>>(rec, send, cursor, perm, sperm);

  // TPS_0 = segsum(e_raw@W_eembed + b_eembed, rec)
  sraw_k<<<dim3(NN / 16), B256, 0, stream>>>(row_ptr, perm, e_in, sraw);
  s0_k<<<dim3(NN / 2), B256, 0, stream>>>(sraw, W_eembed, b_eembed, row_ptr, TPS);

  for (int l = 0; l < 4; ++l){
    const unsigned short* base = wt + 16384 + l * 163840;
    const int two = (l < 3) ? 2 : 1;

    // t_l = sum h[send]
    gather_k<<<dim3(NN / 4), B256, 0, stream>>>(row_ptr, sperm, hb, tb);
    // y0: U = h@Wm2 + Q@Wm3 ; y1: Qnew = h@We2 + Q@We3 (in-place Q)
    gemm2_k<0, 2, 0, 0><<<dim3(313, two), B256, 0, stream>>>(hb, Q, base, NN,
        U, Q, nullptr, nullptr, nullptr, nullptr);
    // y0: agg = t@Wm1 + TPS@Wm3 + deg*(U + r_l) ; y1: TPSnew = t@We1 + TPS@We3 (in-place)
    gemm2_k<0, 2, 1, 0><<<dim3(313, two), B256, 0, stream>>>(tb, TPS, base + 65536, NN,
        agg, TPS, nullptr, U, rvec + l * 128, row_ptr);
    // hnew = h@Wh1 + agg@Wh2 + bh  (in-place h)
    gemm2_k<0, 2, 2, 2><<<dim3(313), B256, 0, stream>>>(hb, agg, base + 131072, NN,
        hb, nullptr, bh + l * 128, nullptr, nullptr, nullptr);
  }

  pool_k<<<dim3(NG / 4), B256, 0, stream>>>(gptr, hb, (float*)d_out);
}